// Round 17
// baseline (58.364 us; speedup 1.0000x reference)
//
#include <hip/hip_runtime.h>

#define NN   25
#define DD   128
#define HH   64
#define KK   4
#define RADF 2.5f

#define XBP  136   // ushort stride, [25][128] bf16 rows (272B)
#define HSP  72    // ushort stride, hxi/hs/nxi/g1 rows (144B)

// ws layout (ushort units) — identical to R12
#define O_W1T  0        // [64][264]  ew1^T (k<259)
#define O_W2NT 16896    // [64][64]   (W2 @ nW1hi)^T
#define O_N1LO 20992    // [64][128]  nW1lo^T
#define O_N2T  29184    // [128][64]  nw2^T
#define O_B2N  37376    // 64 f32 (128 ushorts): b2 @ nW1hi

typedef __attribute__((ext_vector_type(8))) short  short8;
typedef __attribute__((ext_vector_type(4))) float  f32x4;

__device__ __forceinline__ ushort f2bf(float x) {
    uint u = __float_as_uint(x);
    u += 0x7fffu + ((u >> 16) & 1u);          // RNE
    return (ushort)(u >> 16);
}
__device__ __forceinline__ float bf2f(ushort u) {
    return __uint_as_float((uint)u << 16);
}
__device__ __forceinline__ uint pack2(float a, float b) {
    return (uint)f2bf(a) | ((uint)f2bf(b) << 16);
}
__device__ __forceinline__ short8 ldw(const ushort* p) {
    return *reinterpret_cast<const short8*>(p);
}
#define MFMA16(a, b, c) __builtin_amdgcn_mfma_f32_16x16x32_bf16((a), (b), (c), 0, 0, 0)

__global__ void prep_kernel(const float* __restrict__ ew1, const float* __restrict__ ew2,
                            const float* __restrict__ eb2, const float* __restrict__ nw1,
                            const float* __restrict__ nw2, ushort* __restrict__ w) {
    int tid = blockIdx.x * blockDim.x + threadIdx.x;
    int stride = gridDim.x * blockDim.x;
    for (int e = tid; e < 259 * 64; e += stride) {
        int k = e >> 6, c = e & 63;
        w[O_W1T + c * 264 + k] = f2bf(ew1[e]);
    }
    for (int e = tid; e < 64 * 128; e += stride) {
        int c = e >> 7, k = e & 127;
        w[O_N1LO + e] = f2bf(nw1[(size_t)k * 64 + c]);
    }
    for (int e = tid; e < 128 * 64; e += stride) {
        int d = e >> 6, k = e & 63;
        w[O_N2T + e] = f2bf(nw2[(size_t)k * 128 + d]);
    }
    for (int e = tid; e < 64 * 64; e += stride) {
        int c = e >> 6, k = e & 63;
        float acc = 0.f;
        for (int d = 0; d < DD; ++d)
            acc += ew2[(size_t)k * DD + d] * nw1[(size_t)(DD + d) * HH + c];
        w[O_W2NT + e] = f2bf(acc);
    }
    for (int c = tid; c < HH; c += stride) {
        float acc = 0.f;
        for (int d = 0; d < DD; ++d)
            acc += eb2[d] * nw1[(size_t)(DD + d) * HH + c];
        reinterpret_cast<float*>(w + O_B2N)[c] = acc;
    }
}

__global__ __launch_bounds__(128, 4) void ig17_kernel(
    const float* __restrict__ emb,      // [BT,25,128]
    const float* __restrict__ bboxes,   // [BT,25,4]
    const int*   __restrict__ pmask,    // [BT,25]
    const float* __restrict__ ew1f,     // [259,64] f32 (e-rows 256..258)
    const float* __restrict__ eb1,
    const float* __restrict__ nb1,
    const float* __restrict__ nb2,
    const float* __restrict__ lng,
    const float* __restrict__ lnb,
    const ushort* __restrict__ W,       // prepped weights
    float* __restrict__ out)
{
    const int bt  = blockIdx.x;          // one frame per 128-thread block (2 waves)
    const int t   = threadIdx.x;
    const int wv  = t >> 6;              // wave 0/1: NODE half (M-split)
    const int ln  = t & 63;
    const int g   = ln >> 4;             // C-row group (0..3)
    const int r16 = ln & 15;

    const int NB = wv ? 13 : 0;          // own node base
    const int NM = wv ? 12 : 13;         // own node count
    const int nT = wv ? 3 : 4;           // own edge tiles (48 / 52 edges)
    const int ME = NM * KK;              // own edge count

    __shared__ ushort s_xb[NN * XBP];    // 6800 B  bf16 x (shared; only cross-wave data)
    __shared__ ushort s_hxi[NN * HSP];   // 3600 B  hxi, later g1 (per-wave row ranges)
    __shared__ ushort s_hs[NN * HSP];    // 3600 B  hsum (per-wave rows)
    __shared__ ushort s_nxi[NN * HSP];   // 3600 B  x @ nW1lo (per-wave rows)
    __shared__ float  s_ev[NN][KK][4];   // 1600 B  e0,e1,e2,val (per-wave rows)
    __shared__ short  s_idxs[NN][KK];    // 200 B
    __shared__ float  s_meta[NN][4];     // 400 B   cnt,invd,has,mask
    // 19800 B -> 8 blocks/CU -> 16 waves/CU

    ushort* s_g1v = s_hxi;   // g1 overlays hxi (same-wave LDS order guarantees safety)

    // ---------------- P0: stage x (bf16), all 128 threads ----------------
    {
        const float4* src4 = reinterpret_cast<const float4*>(emb + (size_t)bt * (NN * DD));
        for (int u = t; u < NN * 16; u += 128) {
            int row = u >> 4, q = u & 15;
            float4 f0 = src4[row * 32 + q * 2];
            float4 f1 = src4[row * 32 + q * 2 + 1];
            uint4 p;
            p.x = pack2(f0.x, f0.y); p.y = pack2(f0.z, f0.w);
            p.z = pack2(f1.x, f1.y); p.w = pack2(f1.z, f1.w);
            *reinterpret_cast<uint4*>(&s_xb[row * XBP + q * 8]) = p;
        }
    }
    // ---------------- P1: geometry + KNN — BOTH waves compute, each stores own ----
    {
        const int n = (ln < NN) ? ln : NN - 1;
        const float4 b4 = *reinterpret_cast<const float4*>(bboxes + ((size_t)bt * NN + n) * 4);
        const float cxn = b4.x, cyn = b4.y;
        const float hvn = fmaxf(b4.w, 1e-6f);
        const int   mn  = pmask[(size_t)bt * NN + n];
        const float inv = 1.0f / hvn;
        float best[KK] = {1e30f, 1e30f, 1e30f, 1e30f};
        int   bidx[KK] = {0, 0, 0, 0};
        for (int j = 0; j < NN; ++j) {
            float cxj = __shfl(cxn, j);
            float cyj = __shfl(cyn, j);
            int   mj  = __shfl(mn, j);
            float dx = cxn - cxj, dy = cyn - cyj;
            float dn = sqrtf(fmaf(dx, dx, fmaf(dy, dy, 1e-6f))) * inv;
            bool  pv = (mn != 0) && (mj != 0) && (j != n);
            float cv = pv ? dn : 1e6f;
            int   ci = j;
#pragma unroll
            for (int kk = 0; kk < KK; ++kk) {       // stable insertion, lowest idx on tie
                if (cv < best[kk]) {
                    float tv = best[kk]; best[kk] = cv; cv = tv;
                    int   ti = bidx[kk]; bidx[kk] = ci; ci = ti;
                }
            }
        }
        float cnt = 0.f;
        float e0v[KK], e1v[KK], e2v[KK], vvv[KK];
#pragma unroll
        for (int k = 0; k < KK; ++k) {
            int bj = bidx[k];
            float cxb = __shfl(cxn, bj);
            float cyb = __shfl(cyn, bj);
            float val = (best[k] < RADF) ? 1.f : 0.f;
            cnt += val;
            float dx = cxn - cxb, dy = cyn - cyb;
            e0v[k] = dx * inv;
            e1v[k] = dy * inv;
            e2v[k] = sqrtf(fmaf(dx, dx, fmaf(dy, dy, 1e-6f))) * inv;
            vvv[k] = val;
        }
        if (ln >= NB && ln < NB + NM) {   // store ONLY own nodes (global row = ln)
#pragma unroll
            for (int k = 0; k < KK; ++k) {
                s_ev[n][k][0] = e0v[k];
                s_ev[n][k][1] = e1v[k];
                s_ev[n][k][2] = e2v[k];
                s_ev[n][k][3] = vvv[k];
                s_idxs[n][k]  = (short)bidx[k];
            }
            s_meta[n][0] = cnt;
            s_meta[n][1] = 1.0f / fmaxf(cnt, 1.0f);
            s_meta[n][2] = (cnt > 0.f) ? 1.f : 0.f;
            s_meta[n][3] = mn ? 1.f : 0.f;
        }
    }
    __syncthreads();   // B1 — the ONLY barrier: s_xb must be complete for both waves

    // ---------------- F1: {hxi, nxi} = x[own nodes] @ {W1lo, nW1lo} (full 64 cols) -
    {
        const int ra = NB + ((r16 < NM) ? r16 : NM - 1);
        const ushort* A0 = s_xb + ra * XBP + g * 8;
        f32x4 ce[4] = {};
        f32x4 cn[4] = {};
#pragma unroll
        for (int kt = 0; kt < 4; ++kt) {
            short8 a0 = ldw(A0 + kt * 32);
#pragma unroll
            for (int ntl = 0; ntl < 4; ++ntl) {
                short8 be = ldw(W + O_W1T  + (size_t)(16 * ntl + r16) * 264 + kt * 32 + g * 8);
                short8 bn = ldw(W + O_N1LO + (size_t)(16 * ntl + r16) * 128 + kt * 32 + g * 8);
                ce[ntl] = MFMA16(a0, be, ce[ntl]);
                cn[ntl] = MFMA16(a0, bn, cn[ntl]);
            }
        }
#pragma unroll
        for (int q = 0; q < 4; ++q) {
            int nl = 4 * g + q;
            if (nl < NM) {
                int nr = NB + nl;
#pragma unroll
                for (int ntl = 0; ntl < 4; ++ntl) {
                    int col = 16 * ntl + r16;
                    s_hxi[nr * HSP + col] = f2bf(ce[ntl][q]);
                    s_nxi[nr * HSP + col] = f2bf(cn[ntl][q]);
                }
            }
        }
    }

    // ---------------- E1b: xj GEMM over own edges (2 passes x <=2 M-tiles) --------
#pragma unroll
    for (int pass = 0; pass < 2; ++pass) {
        const int T0 = 2 * pass;
        const int tc = (nT - T0 > 2) ? 2 : (nT - T0);   // 2, then 2 or 1
        int jn[2];
#pragma unroll
        for (int i = 0; i < 2; ++i) {
            if (i < tc) {
                int lr = 16 * (T0 + i) + r16; if (lr > ME - 1) lr = ME - 1;
                jn[i] = s_idxs[NB + (lr >> 2)][lr & 3];
            } else jn[i] = 0;
        }
        f32x4 c[2][4] = {};
#pragma unroll
        for (int kt = 0; kt < 4; ++kt) {
            short8 b[4];
#pragma unroll
            for (int ntl = 0; ntl < 4; ++ntl)
                b[ntl] = ldw(W + O_W1T + (size_t)(16 * ntl + r16) * 264 + 128 + kt * 32 + g * 8);
#pragma unroll
            for (int i = 0; i < 2; ++i) {
                if (i < tc) {
                    short8 a = ldw(s_xb + jn[i] * XBP + kt * 32 + g * 8);
#pragma unroll
                    for (int ntl = 0; ntl < 4; ++ntl)
                        c[i][ntl] = MFMA16(a, b[ntl], c[i][ntl]);
                }
            }
        }
        // scalar epilogue (R12-verified): e-channels + bias + hxi, relu, val-k-sum
        float we0[4], we1[4], we2[4], bb1[4];
#pragma unroll
        for (int ntl = 0; ntl < 4; ++ntl) {
            int col = 16 * ntl + r16;
            we0[ntl] = ew1f[256 * 64 + col];
            we1[ntl] = ew1f[257 * 64 + col];
            we2[ntl] = ew1f[258 * 64 + col];
            bb1[ntl] = eb1[col];
        }
#pragma unroll
        for (int i = 0; i < 2; ++i) {
            if (i < tc) {
                const int nl = 4 * (T0 + i) + g;
                if (nl < NM) {
                    const int n = NB + nl;
                    float v0 = s_ev[n][0][3], v1 = s_ev[n][1][3];
                    float v2 = s_ev[n][2][3], v3 = s_ev[n][3][3];
                    float e0q[4], e1q[4], e2q[4];
#pragma unroll
                    for (int q = 0; q < 4; ++q) {
                        e0q[q] = s_ev[n][q][0]; e1q[q] = s_ev[n][q][1]; e2q[q] = s_ev[n][q][2];
                    }
#pragma unroll
                    for (int ntl = 0; ntl < 4; ++ntl) {
                        int col = 16 * ntl + r16;
                        float base = bb1[ntl] + bf2f(s_hxi[n * HSP + col]);
                        float p0 = c[i][ntl][0] + base + e0q[0] * we0[ntl] + e1q[0] * we1[ntl] + e2q[0] * we2[ntl];
                        float p1 = c[i][ntl][1] + base + e0q[1] * we0[ntl] + e1q[1] * we1[ntl] + e2q[1] * we2[ntl];
                        float p2 = c[i][ntl][2] + base + e0q[2] * we0[ntl] + e1q[2] * we1[ntl] + e2q[2] * we2[ntl];
                        float p3 = c[i][ntl][3] + base + e0q[3] * we0[ntl] + e1q[3] * we1[ntl] + e2q[3] * we2[ntl];
                        float hs = fmaf(v0, fmaxf(p0, 0.f),
                                   fmaf(v1, fmaxf(p1, 0.f),
                                   fmaf(v2, fmaxf(p2, 0.f),
                                        v3 * fmaxf(p3, 0.f))));
                        s_hs[n * HSP + col] = f2bf(hs);
                    }
                }
            }
        }
    }
    // no barrier: hs/nxi/hxi rows are wave-local from here on

    // ---------------- N1': g1 = relu(nxi + invd*(hs@W2N + cnt*b2N) + nb1) ---------
    {
        const int ra = NB + ((r16 < NM) ? r16 : NM - 1);
        const ushort* A0 = s_hs + ra * HSP + g * 8;
        f32x4 c[4] = {};
#pragma unroll
        for (int kt = 0; kt < 2; ++kt) {
            short8 a0 = ldw(A0 + kt * 32);
#pragma unroll
            for (int ntl = 0; ntl < 4; ++ntl) {
                short8 b = ldw(W + O_W2NT + (size_t)(16 * ntl + r16) * 64 + kt * 32 + g * 8);
                c[ntl] = MFMA16(a0, b, c[ntl]);
            }
        }
        const float* b2Np = reinterpret_cast<const float*>(W + O_B2N);
#pragma unroll
        for (int ntl = 0; ntl < 4; ++ntl) {
            int col = 16 * ntl + r16;
            float b2n = b2Np[col];
            float b1c = nb1[col];
#pragma unroll
            for (int q = 0; q < 4; ++q) {
                int nl = 4 * g + q;
                if (nl < NM) {
                    int nr = NB + nl;
                    float v = bf2f(s_nxi[nr * HSP + col]) + b1c
                            + s_meta[nr][1] * fmaf(s_meta[nr][0], b2n, c[ntl][q]);
                    s_g1v[nr * HSP + col] = f2bf(fmaxf(v, 0.f));   // overlays hxi (own rows)
                }
            }
        }
    }

    // ---------------- N2: delta GEMM (128 cols) + residual + in-wave LN + store ---
    {
        const int ra = NB + ((r16 < NM) ? r16 : NM - 1);
        const ushort* A0 = s_g1v + ra * HSP + g * 8;
        f32x4 c[8] = {};
#pragma unroll
        for (int kt = 0; kt < 2; ++kt) {
            short8 a0 = ldw(A0 + kt * 32);
#pragma unroll
            for (int ntl = 0; ntl < 8; ++ntl) {
                short8 b = ldw(W + O_N2T + (size_t)(16 * ntl + r16) * 64 + kt * 32 + g * 8);
                c[ntl] = MFMA16(a0, b, c[ntl]);
            }
        }
        float nb2c[8], glc[8], blc[8];
#pragma unroll
        for (int ntl = 0; ntl < 8; ++ntl) {
            int col = 16 * ntl + r16;
            nb2c[ntl] = nb2[col];
            glc[ntl]  = lng[col];
            blc[ntl]  = lnb[col];
        }
#pragma unroll
        for (int q = 0; q < 4; ++q) {
            int nl = 4 * g + q;
            int ncl = (nl < NM) ? nl : NM - 1;
            int nc  = NB + ncl;
            float has = s_meta[nc][2];
            float y[8];
            float a = 0.f, b = 0.f;
#pragma unroll
            for (int ntl = 0; ntl < 8; ++ntl) {
                int col = 16 * ntl + r16;
                float yv = fmaf(has, c[ntl][q] + nb2c[ntl], bf2f(s_xb[nc * XBP + col]));
                y[ntl] = yv;
                a += yv;
                b = fmaf(yv, yv, b);
            }
#pragma unroll
            for (int o = 1; o < 16; o <<= 1) {     // reduce across 16-lane col group
                a += __shfl_xor(a, o);
                b += __shfl_xor(b, o);
            }
            float mu  = a * (1.0f / 128.0f);
            float var = b * (1.0f / 128.0f) - mu * mu;
            float rs  = rsqrtf(var + 1e-5f);
            float mk  = s_meta[nc][3];
            if (nl < NM) {
                float* op = out + (size_t)bt * (NN * DD) + nc * DD;
#pragma unroll
                for (int ntl = 0; ntl < 8; ++ntl) {
                    int col = 16 * ntl + r16;
                    op[col] = fmaf((y[ntl] - mu) * rs, glc[ntl], blc[ntl]) * mk;
                }
            }
        }
    }
}

extern "C" void kernel_launch(void* const* d_in, const int* in_sizes, int n_in,
                              void* d_out, int out_size, void* d_ws, size_t ws_size,
                              hipStream_t stream) {
    const float* emb    = (const float*)d_in[0];
    const float* bboxes = (const float*)d_in[1];
    const int*   pmask  = (const int*)  d_in[2];
    const float* ew1    = (const float*)d_in[3];
    const float* eb1    = (const float*)d_in[4];
    const float* ew2    = (const float*)d_in[5];
    const float* eb2    = (const float*)d_in[6];
    const float* nw1    = (const float*)d_in[7];
    const float* nb1    = (const float*)d_in[8];
    const float* nw2    = (const float*)d_in[9];
    const float* nb2    = (const float*)d_in[10];
    const float* lng    = (const float*)d_in[11];
    const float* lnb    = (const float*)d_in[12];
    float* out = (float*)d_out;
    ushort* W  = (ushort*)d_ws;

    prep_kernel<<<64, 256, 0, stream>>>(ew1, ew2, eb2, nw1, nw2, W);

    const int BT = in_sizes[2] / NN;   // 2048 frames
    ig17_kernel<<<BT, 128, 0, stream>>>(
        emb, bboxes, pmask, ew1, eb1, nb1, nb2, lng, lnb, W, out);
}

// Round 18
// 41.888 us; speedup vs baseline: 1.3933x; 1.3933x over previous
//
#include <hip/hip_runtime.h>

#define NN   25
#define DD   128
#define HH   64
#define KK   4
#define RADF 2.5f

#define XBP  136   // ushort stride, [25][128] bf16 rows (272B)
#define HSP  72    // ushort stride, hxi/hs/nxi/g1 rows (144B)

// ws layout (ushort units) — identical to R12
#define O_W1T  0        // [64][264]  ew1^T (k<259)
#define O_W2NT 16896    // [64][64]   (W2 @ nW1hi)^T
#define O_N1LO 20992    // [64][128]  nW1lo^T
#define O_N2T  29184    // [128][64]  nw2^T
#define O_B2N  37376    // 64 f32 (128 ushorts): b2 @ nW1hi

typedef __attribute__((ext_vector_type(8))) short  short8;
typedef __attribute__((ext_vector_type(4))) float  f32x4;

__device__ __forceinline__ ushort f2bf(float x) {
    uint u = __float_as_uint(x);
    u += 0x7fffu + ((u >> 16) & 1u);          // RNE
    return (ushort)(u >> 16);
}
__device__ __forceinline__ float bf2f(ushort u) {
    return __uint_as_float((uint)u << 16);
}
__device__ __forceinline__ uint pack2(float a, float b) {
    return (uint)f2bf(a) | ((uint)f2bf(b) << 16);
}
__device__ __forceinline__ short8 ldw(const ushort* p) {
    return *reinterpret_cast<const short8*>(p);
}
#define MFMA16(a, b, c) __builtin_amdgcn_mfma_f32_16x16x32_bf16((a), (b), (c), 0, 0, 0)

__global__ void prep_kernel(const float* __restrict__ ew1, const float* __restrict__ ew2,
                            const float* __restrict__ eb2, const float* __restrict__ nw1,
                            const float* __restrict__ nw2, ushort* __restrict__ w) {
    int tid = blockIdx.x * blockDim.x + threadIdx.x;
    int stride = gridDim.x * blockDim.x;
    for (int e = tid; e < 259 * 64; e += stride) {
        int k = e >> 6, c = e & 63;
        w[O_W1T + c * 264 + k] = f2bf(ew1[e]);       // read coalesced
    }
    for (int e = tid; e < 64 * 128; e += stride) {
        int c = e >> 7, k = e & 127;
        w[O_N1LO + e] = f2bf(nw1[(size_t)k * 64 + c]);
    }
    for (int e = tid; e < 128 * 64; e += stride) {
        int d = e >> 6, k = e & 63;
        w[O_N2T + e] = f2bf(nw2[(size_t)k * 128 + d]);
    }
    // W2N^T: COALESCED mapping — within a wave, k fixed (ew2 row broadcast),
    // c consecutive (nw1 reads coalesced). Writes scattered but tiny (8KB).
    for (int e = tid; e < 64 * 64; e += stride) {
        int k = e >> 6, c = e & 63;
        float acc = 0.f;
        for (int d = 0; d < DD; ++d)
            acc += ew2[(size_t)k * DD + d] * nw1[(size_t)(DD + d) * HH + c];
        w[O_W2NT + c * 64 + k] = f2bf(acc);
    }
    for (int c = tid; c < HH; c += stride) {
        float acc = 0.f;
        for (int d = 0; d < DD; ++d)
            acc += eb2[d] * nw1[(size_t)(DD + d) * HH + c];
        reinterpret_cast<float*>(w + O_B2N)[c] = acc;
    }
}

__global__ __launch_bounds__(128, 4) void ig18_kernel(
    const float* __restrict__ emb,      // [BT,25,128]
    const float* __restrict__ bboxes,   // [BT,25,4]
    const int*   __restrict__ pmask,    // [BT,25]
    const float* __restrict__ ew1f,     // [259,64] f32 (e-rows 256..258)
    const float* __restrict__ eb1,
    const float* __restrict__ nb1,
    const float* __restrict__ nb2,
    const float* __restrict__ lng,
    const float* __restrict__ lnb,
    const ushort* __restrict__ W,       // prepped weights
    float* __restrict__ out)
{
    const int bt  = blockIdx.x;          // one frame per 128-thread block (2 waves)
    const int t   = threadIdx.x;
    const int wv  = t >> 6;              // wave 0/1: N-column half
    const int ln  = t & 63;
    const int g   = ln >> 4;             // k-chunk / C-row group (0..3)
    const int r16 = ln & 15;
    const int cb  = 2 * wv;              // col-tile base for 64-col phases
    const int cb4 = 4 * wv;              // col-tile base for 128-col phases

    __shared__ ushort s_xb[NN * XBP];            // 6800 B  bf16 x
    __shared__ ushort s_hxi[NN * HSP];           // 3600 B  hxi, later g1 overlay
    __shared__ ushort s_hs[NN * HSP];            // 3600 B  hsum
    __shared__ ushort s_nxi[NN * HSP];           // 3600 B  x @ nW1lo
    __shared__ __align__(16) char s_misc[1600];  // s_ev, later s_red overlay
    __shared__ short  s_idxs[NN][KK];            // 200 B
    __shared__ float  s_meta[NN][4];             // 400 B  cnt,invd,has,mask
    // ~19.8 KB -> 8 blocks/CU -> 16 waves/CU

    float (*s_ev)[KK][4] = reinterpret_cast<float(*)[KK][4]>(s_misc);  // dead after E1b
    float (*s_red)[2][2] = reinterpret_cast<float(*)[2][2]>(s_misc);   // N2 overlay
    ushort* s_g1v = s_hxi;   // g1 overlays hxi (hxi dead after E1b epilogue)

    if (wv == 0) {
        // ---------------- P0: stage x (bf16), wave 0 ----------------
        const float4* src4 = reinterpret_cast<const float4*>(emb + (size_t)bt * (NN * DD));
        for (int u = ln; u < NN * 16; u += 64) {
            int row = u >> 4, q = u & 15;
            float4 f0 = src4[row * 32 + q * 2];
            float4 f1 = src4[row * 32 + q * 2 + 1];
            uint4 p;
            p.x = pack2(f0.x, f0.y); p.y = pack2(f0.z, f0.w);
            p.z = pack2(f1.x, f1.y); p.w = pack2(f1.z, f1.w);
            *reinterpret_cast<uint4*>(&s_xb[row * XBP + q * 8]) = p;
        }
    } else {
        // ---------------- P1: geometry + KNN (shuffle-based), wave 1 --------------
        const int n = (ln < NN) ? ln : NN - 1;
        const float4 b4 = *reinterpret_cast<const float4*>(bboxes + ((size_t)bt * NN + n) * 4);
        const float cxn = b4.x, cyn = b4.y;
        const float hvn = fmaxf(b4.w, 1e-6f);
        const int   mn  = pmask[(size_t)bt * NN + n];
        const float inv = 1.0f / hvn;
        float best[KK] = {1e30f, 1e30f, 1e30f, 1e30f};
        int   bidx[KK] = {0, 0, 0, 0};
        for (int j = 0; j < NN; ++j) {
            float cxj = __shfl(cxn, j);
            float cyj = __shfl(cyn, j);
            int   mj  = __shfl(mn, j);
            float dx = cxn - cxj, dy = cyn - cyj;
            float dn = sqrtf(fmaf(dx, dx, fmaf(dy, dy, 1e-6f))) * inv;
            bool  pv = (mn != 0) && (mj != 0) && (j != n);
            float cv = pv ? dn : 1e6f;
            int   ci = j;
#pragma unroll
            for (int kk = 0; kk < KK; ++kk) {       // stable insertion, lowest idx on tie
                if (cv < best[kk]) {
                    float tv = best[kk]; best[kk] = cv; cv = tv;
                    int   ti = bidx[kk]; bidx[kk] = ci; ci = ti;
                }
            }
        }
        float cnt = 0.f;
        float e0v[KK], e1v[KK], e2v[KK], vvv[KK];
#pragma unroll
        for (int k = 0; k < KK; ++k) {
            int bj = bidx[k];
            float cxb = __shfl(cxn, bj);
            float cyb = __shfl(cyn, bj);
            float val = (best[k] < RADF) ? 1.f : 0.f;
            cnt += val;
            float dx = cxn - cxb, dy = cyn - cyb;
            e0v[k] = dx * inv;
            e1v[k] = dy * inv;
            e2v[k] = sqrtf(fmaf(dx, dx, fmaf(dy, dy, 1e-6f))) * inv;
            vvv[k] = val;
        }
        if (ln < NN) {
#pragma unroll
            for (int k = 0; k < KK; ++k) {
                s_ev[n][k][0] = e0v[k];
                s_ev[n][k][1] = e1v[k];
                s_ev[n][k][2] = e2v[k];
                s_ev[n][k][3] = vvv[k];
                s_idxs[n][k]  = (short)bidx[k];
            }
            s_meta[n][0] = cnt;
            s_meta[n][1] = 1.0f / fmaxf(cnt, 1.0f);
            s_meta[n][2] = (cnt > 0.f) ? 1.f : 0.f;
            s_meta[n][3] = mn ? 1.f : 0.f;
        }
    }
    __syncthreads();   // B1

    // ---------------- F1: {hxi, nxi} = x @ {W1lo, nW1lo}  (shared A pass) ---------
    {
        int na1 = 16 + r16; if (na1 > 24) na1 = 24;
        const ushort* A0 = s_xb + r16 * XBP + g * 8;
        const ushort* A1 = s_xb + na1 * XBP + g * 8;
        f32x4 ce[2][2] = {};
        f32x4 cn[2][2] = {};
#pragma unroll
        for (int kt = 0; kt < 4; ++kt) {
            short8 a0 = ldw(A0 + kt * 32);
            short8 a1 = ldw(A1 + kt * 32);
#pragma unroll
            for (int ntl = 0; ntl < 2; ++ntl) {
                short8 be = ldw(W + O_W1T  + (size_t)(16 * (cb + ntl) + r16) * 264 + kt * 32 + g * 8);
                short8 bn = ldw(W + O_N1LO + (size_t)(16 * (cb + ntl) + r16) * 128 + kt * 32 + g * 8);
                ce[0][ntl] = MFMA16(a0, be, ce[0][ntl]);
                ce[1][ntl] = MFMA16(a1, be, ce[1][ntl]);
                cn[0][ntl] = MFMA16(a0, bn, cn[0][ntl]);
                cn[1][ntl] = MFMA16(a1, bn, cn[1][ntl]);
            }
        }
#pragma unroll
        for (int mt = 0; mt < 2; ++mt)
#pragma unroll
            for (int q = 0; q < 4; ++q) {
                int nr = 16 * mt + 4 * g + q;
                if (nr < 25) {
#pragma unroll
                    for (int ntl = 0; ntl < 2; ++ntl) {
                        int col = 16 * (cb + ntl) + r16;
                        s_hxi[nr * HSP + col] = f2bf(ce[mt][ntl][q]);
                        s_nxi[nr * HSP + col] = f2bf(cn[mt][ntl][q]);
                    }
                }
            }
    }
    // no barrier: hxi/nxi cols are wave-local

    // ---------------- E1b: xj GEMM, 1 weight pass over 7 M-tiles ------------------
    {
        int jn[7];
#pragma unroll
        for (int T = 0; T < 7; ++T) {
            int r = 16 * T + r16; if (r > 99) r = 99;
            jn[T] = s_idxs[r >> 2][r & 3];
        }
        f32x4 c[7][2] = {};
#pragma unroll
        for (int kt = 0; kt < 4; ++kt) {
            short8 b0 = ldw(W + O_W1T + (size_t)(16 * (cb + 0) + r16) * 264 + 128 + kt * 32 + g * 8);
            short8 b1 = ldw(W + O_W1T + (size_t)(16 * (cb + 1) + r16) * 264 + 128 + kt * 32 + g * 8);
#pragma unroll
            for (int T = 0; T < 7; ++T) {
                short8 a = ldw(s_xb + jn[T] * XBP + kt * 32 + g * 8);
                c[T][0] = MFMA16(a, b0, c[T][0]);
                c[T][1] = MFMA16(a, b1, c[T][1]);
            }
        }
        float we0[2], we1[2], we2[2], bb1[2];
#pragma unroll
        for (int ntl = 0; ntl < 2; ++ntl) {
            int col = 16 * (cb + ntl) + r16;
            we0[ntl] = ew1f[256 * 64 + col];
            we1[ntl] = ew1f[257 * 64 + col];
            we2[ntl] = ew1f[258 * 64 + col];
            bb1[ntl] = eb1[col];
        }
#pragma unroll
        for (int T = 0; T < 7; ++T) {
            const int n = 4 * T + g;
            if (n < 25) {
                float v0 = s_ev[n][0][3], v1 = s_ev[n][1][3];
                float v2 = s_ev[n][2][3], v3 = s_ev[n][3][3];
                float e0q[4], e1q[4], e2q[4];
#pragma unroll
                for (int q = 0; q < 4; ++q) {
                    e0q[q] = s_ev[n][q][0]; e1q[q] = s_ev[n][q][1]; e2q[q] = s_ev[n][q][2];
                }
#pragma unroll
                for (int ntl = 0; ntl < 2; ++ntl) {
                    int col = 16 * (cb + ntl) + r16;
                    float base = bb1[ntl] + bf2f(s_hxi[n * HSP + col]);
                    float p0 = c[T][ntl][0] + base + e0q[0] * we0[ntl] + e1q[0] * we1[ntl] + e2q[0] * we2[ntl];
                    float p1 = c[T][ntl][1] + base + e0q[1] * we0[ntl] + e1q[1] * we1[ntl] + e2q[1] * we2[ntl];
                    float p2 = c[T][ntl][2] + base + e0q[2] * we0[ntl] + e1q[2] * we1[ntl] + e2q[2] * we2[ntl];
                    float p3 = c[T][ntl][3] + base + e0q[3] * we0[ntl] + e1q[3] * we1[ntl] + e2q[3] * we2[ntl];
                    float hs = fmaf(v0, fmaxf(p0, 0.f),
                               fmaf(v1, fmaxf(p1, 0.f),
                               fmaf(v2, fmaxf(p2, 0.f),
                                    v3 * fmaxf(p3, 0.f))));
                    s_hs[n * HSP + col] = f2bf(hs);
                }
            }
        }
    }
    __syncthreads();   // B2: hs needed across waves (and hxi dead -> g1 may overlay)

    // ---------------- N1': g1 = relu(nxi + invd*(hs@W2N + cnt*b2N) + nb1) ---------
    {
        int na1 = 16 + r16; if (na1 > 24) na1 = 24;
        const ushort* A0 = s_hs + r16 * HSP + g * 8;
        const ushort* A1 = s_hs + na1 * HSP + g * 8;
        f32x4 c[2][2] = {};
#pragma unroll
        for (int kt = 0; kt < 2; ++kt) {
            short8 a0 = ldw(A0 + kt * 32);
            short8 a1 = ldw(A1 + kt * 32);
#pragma unroll
            for (int ntl = 0; ntl < 2; ++ntl) {
                short8 b = ldw(W + O_W2NT + (size_t)(16 * (cb + ntl) + r16) * 64 + kt * 32 + g * 8);
                c[0][ntl] = MFMA16(a0, b, c[0][ntl]);
                c[1][ntl] = MFMA16(a1, b, c[1][ntl]);
            }
        }
        const float* b2Np = reinterpret_cast<const float*>(W + O_B2N);
#pragma unroll
        for (int ntl = 0; ntl < 2; ++ntl) {
            int col = 16 * (cb + ntl) + r16;
            float b2n = b2Np[col];
            float b1c = nb1[col];
#pragma unroll
            for (int mt = 0; mt < 2; ++mt)
#pragma unroll
                for (int q = 0; q < 4; ++q) {
                    int nr = 16 * mt + 4 * g + q;
                    if (nr < 25) {
                        float v = bf2f(s_nxi[nr * HSP + col]) + b1c
                                + s_meta[nr][1] * fmaf(s_meta[nr][0], b2n, c[mt][ntl][q]);
                        s_g1v[nr * HSP + col] = f2bf(fmaxf(v, 0.f));
                    }
                }
        }
    }
    __syncthreads();   // B3: g1 needed across waves

    // ---------------- N2: delta GEMM + residual + LN partials + store -------------
    {
        int na1 = 16 + r16; if (na1 > 24) na1 = 24;
        const ushort* A0 = s_g1v + r16 * HSP + g * 8;
        const ushort* A1 = s_g1v + na1 * HSP + g * 8;
        f32x4 c[2][4] = {};
#pragma unroll
        for (int kt = 0; kt < 2; ++kt) {
            short8 a0 = ldw(A0 + kt * 32);
            short8 a1 = ldw(A1 + kt * 32);
#pragma unroll
            for (int ntl = 0; ntl < 4; ++ntl) {
                short8 b = ldw(W + O_N2T + (size_t)(16 * (cb4 + ntl) + r16) * 64 + kt * 32 + g * 8);
                c[0][ntl] = MFMA16(a0, b, c[0][ntl]);
                c[1][ntl] = MFMA16(a1, b, c[1][ntl]);
            }
        }
        float nb2c[4], glc[4], blc[4];
#pragma unroll
        for (int ntl = 0; ntl < 4; ++ntl) {
            int col = 16 * (cb4 + ntl) + r16;
            nb2c[ntl] = nb2[col];
            glc[ntl]  = lng[col];
            blc[ntl]  = lnb[col];
        }
        float y[2][4][4];
#pragma unroll
        for (int mt = 0; mt < 2; ++mt) {
#pragma unroll
            for (int q = 0; q < 4; ++q) {
                int nr = 16 * mt + 4 * g + q;
                int nc = nr < 25 ? nr : 24;
                float has = s_meta[nc][2];
                float a = 0.f, b = 0.f;
#pragma unroll
                for (int ntl = 0; ntl < 4; ++ntl) {
                    int col = 16 * (cb4 + ntl) + r16;
                    float yv = fmaf(has, c[mt][ntl][q] + nb2c[ntl], bf2f(s_xb[nc * XBP + col]));
                    y[mt][ntl][q] = yv;
                    a += yv;
                    b = fmaf(yv, yv, b);
                }
#pragma unroll
                for (int o = 1; o < 16; o <<= 1) {
                    a += __shfl_xor(a, o);
                    b += __shfl_xor(b, o);
                }
                if (r16 == 0 && nr < 25) {
                    s_red[nr][wv][0] = a;
                    s_red[nr][wv][1] = b;
                }
            }
        }
        __syncthreads();   // B4: both waves' LN partials in place
#pragma unroll
        for (int mt = 0; mt < 2; ++mt) {
#pragma unroll
            for (int q = 0; q < 4; ++q) {
                int nr = 16 * mt + 4 * g + q;
                int nc = nr < 25 ? nr : 24;
                float S   = s_red[nc][0][0] + s_red[nc][1][0];
                float S2  = s_red[nc][0][1] + s_red[nc][1][1];
                float mu  = S * (1.0f / 128.0f);
                float var = S2 * (1.0f / 128.0f) - mu * mu;
                float rs  = rsqrtf(var + 1e-5f);
                float mk  = s_meta[nc][3];
                if (nr < 25) {
                    float* op = out + (size_t)bt * (NN * DD) + nr * DD;
#pragma unroll
                    for (int ntl = 0; ntl < 4; ++ntl) {
                        int col = 16 * (cb4 + ntl) + r16;
                        op[col] = fmaf((y[mt][ntl][q] - mu) * rs, glc[ntl], blc[ntl]) * mk;
                    }
                }
            }
        }
    }
}

extern "C" void kernel_launch(void* const* d_in, const int* in_sizes, int n_in,
                              void* d_out, int out_size, void* d_ws, size_t ws_size,
                              hipStream_t stream) {
    const float* emb    = (const float*)d_in[0];
    const float* bboxes = (const float*)d_in[1];
    const int*   pmask  = (const int*)  d_in[2];
    const float* ew1    = (const float*)d_in[3];
    const float* eb1    = (const float*)d_in[4];
    const float* ew2    = (const float*)d_in[5];
    const float* eb2    = (const float*)d_in[6];
    const float* nw1    = (const float*)d_in[7];
    const float* nb1    = (const float*)d_in[8];
    const float* nw2    = (const float*)d_in[9];
    const float* nb2    = (const float*)d_in[10];
    const float* lng    = (const float*)d_in[11];
    const float* lnb    = (const float*)d_in[12];
    float* out = (float*)d_out;
    ushort* W  = (ushort*)d_ws;

    prep_kernel<<<64, 256, 0, stream>>>(ew1, ew2, eb2, nw1, nw2, W);

    const int BT = in_sizes[2] / NN;   // 2048 frames
    ig18_kernel<<<BT, 128, 0, stream>>>(
        emb, bboxes, pmask, ew1, eb1, nb1, nb2, lng, lnb, W, out);
}